// Round 3
// baseline (912.257 us; speedup 1.0000x reference)
//
#include <hip/hip_runtime.h>
#include <cstdint>

using u16 = unsigned short;
using u32 = unsigned int;

typedef __bf16 bf16x8 __attribute__((ext_vector_type(8)));
typedef float f32x4 __attribute__((ext_vector_type(4)));

constexpr int TOK = 100352;                 // B * H * W
constexpr float SCALE_Q = 0.17677669529663687f;   // 1/sqrt(32)

__device__ __forceinline__ float bf2f(u16 u) {
  union { u32 i; float f; } z; z.i = ((u32)u) << 16; return z.f;
}
__device__ __forceinline__ u16 f2bf(float f) {
  union { float f; u32 i; } z; z.f = f;
  u32 r = z.i + 0x7FFFu + ((z.i >> 16) & 1u);
  return (u16)(r >> 16);
}

__device__ __forceinline__ void gload_lds16(const void* g, void* l) {
  __builtin_amdgcn_global_load_lds((const __attribute__((address_space(1))) void*)g,
                                   (__attribute__((address_space(3))) void*)l, 16, 0, 0);
}

// -------------------- weight transpose + zero-pad to Npad rows --------------------
__global__ void transpose_pad(const float* __restrict__ src, u16* __restrict__ dst,
                              int N, int Npad, int K) {
  int id = blockIdx.x * 256 + threadIdx.x;
  if (id >= Npad * K) return;
  int n = id / K, k = id - n * K;
  float v = (n < N) ? src[(size_t)k * N + n] : 0.f;
  dst[id] = f2bf(v);
}

// -------------------- layernorm (one wave per 192-wide row) --------------------
template<int MODE>  // 0: ln(x) ; 1: ln(x + proj_bf16)
__global__ __launch_bounds__(256) void ln_kernel(const float* __restrict__ x,
                                                 const u16* __restrict__ proj,
                                                 const float* __restrict__ g,
                                                 const float* __restrict__ b,
                                                 u16* __restrict__ out) {
  int row  = blockIdx.x * 4 + (threadIdx.x >> 6);
  int lane = threadIdx.x & 63;
  const float* xr = x + (size_t)row * 192;
  float v[3];
  #pragma unroll
  for (int t = 0; t < 3; ++t) {
    int c = lane + 64 * t;
    v[t] = xr[c];
    if (MODE == 1) v[t] += bf2f(proj[(size_t)row * 192 + c]);
  }
  float s = v[0] + v[1] + v[2];
  #pragma unroll
  for (int o = 32; o; o >>= 1) s += __shfl_xor(s, o);
  float mu = s * (1.f / 192.f);
  float q = 0.f;
  #pragma unroll
  for (int t = 0; t < 3; ++t) { float d = v[t] - mu; q += d * d; }
  #pragma unroll
  for (int o = 32; o; o >>= 1) q += __shfl_xor(q, o);
  float rs = rsqrtf(q * (1.f / 192.f) + 1e-5f);
  #pragma unroll
  for (int t = 0; t < 3; ++t) {
    int c = lane + 64 * t;
    out[(size_t)row * 192 + c] = f2bf((v[t] - mu) * rs * g[c] + b[c]);
  }
}

// -------------------- MFMA GEMM: C[M x N] = A[M x K] @ BT[N x K]^T + epilogue ----
enum { MQKV = 0, MPROJ = 1 };

template<int MODE>
__global__ __launch_bounds__(256) void gemm_kernel(
    const u16* __restrict__ A, const u16* __restrict__ BT,
    int K, int ldbt, int N, int ldc,
    const float* __restrict__ bias,
    u16* __restrict__ outb)
{
  __shared__ __align__(16) u16 As[128 * 32];
  __shared__ __align__(16) u16 Bs[128 * 32];
  int tid = threadIdx.x;
  int tileM = blockIdx.x * 128, tileN = blockIdx.y * 128;
  int lane = tid & 63, wave = tid >> 6;
  int wm = wave >> 1, wn = wave & 1;
  f32x4 acc[4][4] = {};

  int r0 = tid >> 2, kc = (tid & 3) * 8;
  const u16* Arow0 = A  + (size_t)(tileM + r0)      * K    + kc;
  const u16* Arow1 = A  + (size_t)(tileM + r0 + 64) * K    + kc;
  const u16* Brow0 = BT + (size_t)(tileN + r0)      * ldbt + kc;
  const u16* Brow1 = BT + (size_t)(tileN + r0 + 64) * ldbt + kc;
  u16* AsW0 = As + wave * 512;
  u16* AsW1 = As + 2048 + wave * 512;
  u16* BsW0 = Bs + wave * 512;
  u16* BsW1 = Bs + 2048 + wave * 512;

  for (int k0 = 0; k0 < K; k0 += 32) {
    __syncthreads();
    gload_lds16(Arow0 + k0, AsW0);
    gload_lds16(Arow1 + k0, AsW1);
    gload_lds16(Brow0 + k0, BsW0);
    gload_lds16(Brow1 + k0, BsW1);
    __syncthreads();
    bf16x8 af[4], bfr[4];
    #pragma unroll
    for (int mi = 0; mi < 4; ++mi)
      af[mi] = *(const bf16x8*)&As[(wm * 64 + mi * 16 + (lane & 15)) * 32 + (lane >> 4) * 8];
    #pragma unroll
    for (int ni = 0; ni < 4; ++ni)
      bfr[ni] = *(const bf16x8*)&Bs[(wn * 64 + ni * 16 + (lane & 15)) * 32 + (lane >> 4) * 8];
    #pragma unroll
    for (int mi = 0; mi < 4; ++mi)
      #pragma unroll
      for (int ni = 0; ni < 4; ++ni)
        acc[mi][ni] = __builtin_amdgcn_mfma_f32_16x16x32_bf16(af[mi], bfr[ni], acc[mi][ni], 0, 0, 0);
  }

  int rbase = tileM + wm * 64 + ((lane >> 4) << 2);
  int cbase = tileN + wn * 64 + (lane & 15);
  #pragma unroll
  for (int ni = 0; ni < 4; ++ni) {
    int col = cbase + ni * 16;
    if (col >= N) continue;
    float bv = bias[col];
    #pragma unroll
    for (int mi = 0; mi < 4; ++mi) {
      #pragma unroll
      for (int i = 0; i < 4; ++i) {
        int row = rbase + mi * 16 + i;
        float v = acc[mi][ni][i] + bv;
        if (MODE == MQKV && col < 192) v *= SCALE_Q;
        outb[(size_t)row * ldc + col] = f2bf(v);
      }
    }
  }
}

// -------------------- fused MLP: out = x + proj + fc2(gelu(fc1(h2))) ----------
// 784 blocks x 256 threads (4 waves). 128 rows/block, wave owns 32 rows.
// 12 chunks of 64 gelu-cols; W1/W2 chunk reg-staged to padded LDS; G wave-private.
constexpr int XS  = 194;   // X row stride (192 + 2 pad)  -> 97 dw % 32 = 1, conflict-free
constexpr int WS1 = 194;   // W1 row stride
constexpr int WS2 = 66;    // W2 row stride (64 + 2 pad)  -> 33 dw % 32 = 1
constexpr int GS  = 66;    // G row stride

__global__ __launch_bounds__(256, 1) void mlp_kernel(
    const u16* __restrict__ h2, const float* __restrict__ x,
    const u16* __restrict__ projO,
    const u16* __restrict__ fc1T,   // [768][192] bf16
    const u16* __restrict__ fc2T,   // [192][768] bf16
    const float* __restrict__ fc1b, const float* __restrict__ fc2b,
    float* __restrict__ out)
{
  __shared__ __align__(16) u16 LDS[58368];   // 116.7 KB
  u16* X  = LDS;                      // [128][194]
  u16* W1 = LDS + 24832;              // [64][194]
  u16* W2 = LDS + 24832 + 12416;      // [192][66]
  u16* G  = LDS + 24832 + 12416 + 12672;  // 4 x [32][66]

  int tid = threadIdx.x, lane = tid & 63, wave = tid >> 6;
  int g = lane >> 4, l15 = lane & 15;
  size_t row0 = (size_t)blockIdx.x * 128;

  // stage X (h2 tile) once: 128 rows x 24 chunks of 16B
  for (int c = tid; c < 3072; c += 256) {
    int r = c / 24, kc = c - r * 24;
    *(uint4*)&X[r * XS + kc * 8] = *(const uint4*)&h2[(row0 + r) * 192 + kc * 8];
  }

  f32x4 accO[2][12] = {};
  u16* Gw = G + wave * (32 * GS);

  for (int ch = 0; ch < 12; ++ch) {
    __syncthreads();   // prior chunk's W reads done
    // stage W1 chunk [64 gc][192 k]: 1536 chunks
    for (int c = tid; c < 1536; c += 256) {
      int r = c / 24, kc = c - r * 24;
      *(uint4*)&W1[r * WS1 + kc * 8] = *(const uint4*)&fc1T[((size_t)(ch * 64 + r)) * 192 + kc * 8];
    }
    // stage W2 chunk [192 oc][64 k]: 1536 chunks
    for (int c = tid; c < 1536; c += 256) {
      int r = c / 8, kc = c - r * 8;
      *(uint4*)&W2[r * WS2 + kc * 8] = *(const uint4*)&fc2T[(size_t)r * 768 + ch * 64 + kc * 8];
    }
    __syncthreads();

    // ---- fc1: S[32 r][64 gc] = X @ W1c^T ----
    f32x4 acc1[2][4] = {};
    #pragma unroll
    for (int ks = 0; ks < 6; ++ks) {
      bf16x8 xf[2], wf[4];
      #pragma unroll
      for (int mi = 0; mi < 2; ++mi)
        xf[mi] = *(const bf16x8*)&X[(wave * 32 + mi * 16 + l15) * XS + ks * 32 + g * 8];
      #pragma unroll
      for (int ni = 0; ni < 4; ++ni)
        wf[ni] = *(const bf16x8*)&W1[(ni * 16 + l15) * WS1 + ks * 32 + g * 8];
      #pragma unroll
      for (int mi = 0; mi < 2; ++mi)
        #pragma unroll
        for (int ni = 0; ni < 4; ++ni)
          acc1[mi][ni] = __builtin_amdgcn_mfma_f32_16x16x32_bf16(xf[mi], wf[ni], acc1[mi][ni], 0, 0, 0);
    }

    // ---- gelu + write wave-private G[32 r][64 gc] ----
    #pragma unroll
    for (int ni = 0; ni < 4; ++ni) {
      float bv = fc1b[ch * 64 + ni * 16 + l15];
      #pragma unroll
      for (int mi = 0; mi < 2; ++mi)
        #pragma unroll
        for (int r = 0; r < 4; ++r) {
          float v = acc1[mi][ni][r] + bv;
          v = 0.5f * v * (1.f + erff(v * 0.70710678118f));
          Gw[(mi * 16 + g * 4 + r) * GS + ni * 16 + l15] = f2bf(v);
        }
    }
    asm volatile("s_waitcnt lgkmcnt(0)" ::: "memory");
    __builtin_amdgcn_sched_barrier(0);

    // ---- fc2 accumulate: out[32 r][192 oc] += G @ W2c^T ----
    #pragma unroll
    for (int ks = 0; ks < 2; ++ks) {
      bf16x8 gf[2];
      #pragma unroll
      for (int mi = 0; mi < 2; ++mi)
        gf[mi] = *(const bf16x8*)&Gw[(mi * 16 + l15) * GS + ks * 32 + g * 8];
      #pragma unroll
      for (int ni = 0; ni < 12; ++ni) {
        bf16x8 wf = *(const bf16x8*)&W2[(ni * 16 + l15) * WS2 + ks * 32 + g * 8];
        #pragma unroll
        for (int mi = 0; mi < 2; ++mi)
          accO[mi][ni] = __builtin_amdgcn_mfma_f32_16x16x32_bf16(gf[mi], wf, accO[mi][ni], 0, 0, 0);
      }
    }
  }

  // ---- epilogue: out = accO + fc2_b + x + projO ----
  #pragma unroll
  for (int ni = 0; ni < 12; ++ni) {
    int oc = ni * 16 + l15;
    float bv = fc2b[oc];
    #pragma unroll
    for (int mi = 0; mi < 2; ++mi)
      #pragma unroll
      for (int r = 0; r < 4; ++r) {
        size_t row = row0 + wave * 32 + mi * 16 + g * 4 + r;
        size_t o = row * 192 + oc;
        out[o] = accO[mi][ni][r] + bv + x[o] + bf2f(projO[o]);
      }
  }
}

// -------------------- MFMA windowed attention --------------------
__global__ __launch_bounds__(384, 3) void attn_kernel(const u16* __restrict__ qkv,
                                                      const float* __restrict__ rpe,
                                                      u16* __restrict__ aout) {
  __shared__ __align__(16) u16 SH[64 * 384];
  __shared__ __align__(16) u16 VT[192 * 72];
  __shared__ float RPE[1014];

  int tid = threadIdx.x;
  int win = blockIdx.x;
  int b = win >> 6, rem = win & 63, wh = rem >> 3, ww = rem & 7;
  const size_t wbase = (size_t)b * 3136 + (size_t)(wh * 7) * 56 + ww * 7;

  for (int c = tid; c < 2352; c += 384) {
    int tkn = c / 48, off = (c - tkn * 48) * 8;
    int yi = tkn / 7, xi = tkn - yi * 7;
    size_t t = wbase + yi * 56 + xi;
    uint4 v = *(const uint4*)&qkv[t * 576 + off];
    *(uint4*)&SH[(tkn * 384 + off) ^ ((tkn & 7) << 3)] = v;
  }
  for (int c = tid; c < 1176; c += 384) {
    int tkn = c / 24, d0 = (c - tkn * 24) * 8;
    int yi = tkn / 7, xi = tkn - yi * 7;
    size_t t = wbase + yi * 56 + xi;
    uint4 v = *(const uint4*)&qkv[t * 576 + 384 + d0];
    const u16* e = (const u16*)&v;
    #pragma unroll
    for (int u = 0; u < 8; ++u) VT[(d0 + u) * 72 + tkn] = e[u];
  }
  for (int c = tid; c < 2880; c += 384) {
    int d = c / 15, n = 49 + (c - d * 15);
    VT[d * 72 + n] = 0;
  }
  for (int c = tid; c < 1014; c += 384) RPE[c] = rpe[c];
  __syncthreads();

  int wave = tid >> 6, lane = tid & 63;
  int g = lane >> 4, l15 = lane & 15;
  int h = wave;

  bf16x8 afk[4], bfq[4];
  #pragma unroll
  for (int f = 0; f < 4; ++f) {
    int row = f * 16 + l15;
    int sw = (row & 7) << 3;
    afk[f] = *(const bf16x8*)&SH[(row * 384 + 192 + h * 32 + g * 8) ^ sw];
    bfq[f] = *(const bf16x8*)&SH[(row * 384 +       h * 32 + g * 8) ^ sw];
  }
  f32x4 acc[4][4] = {};
  #pragma unroll
  for (int mj = 0; mj < 4; ++mj)
    #pragma unroll
    for (int ni = 0; ni < 4; ++ni)
      acc[mj][ni] = __builtin_amdgcn_mfma_f32_16x16x32_bf16(afk[mj], bfq[ni], acc[mj][ni], 0, 0, 0);
  __syncthreads();

  const int psb = wave * 4096;
  float sums[4];
  #pragma unroll
  for (int ni = 0; ni < 4; ++ni) {
    int i = ni * 16 + l15;
    int yi = i / 7, xi = i - yi * 7;
    #pragma unroll
    for (int mj = 0; mj < 4; ++mj)
      #pragma unroll
      for (int r = 0; r < 4; ++r) {
        int j = mj * 16 + g * 4 + r;
        int yj = j / 7, xj = j - yj * 7;
        int idx = (yi - yj + 6) * 13 + (xi - xj + 6);
        idx = max(0, min(idx, 168));
        float s = acc[mj][ni][r] + RPE[idx * 6 + h];
        acc[mj][ni][r] = (j < 49) ? s : -1e30f;
      }
    float m = -1e30f;
    #pragma unroll
    for (int mj = 0; mj < 4; ++mj) {
      f32x4 a = acc[mj][ni];
      m = fmaxf(m, fmaxf(fmaxf(a[0], a[1]), fmaxf(a[2], a[3])));
    }
    m = fmaxf(m, __shfl_xor(m, 16));
    m = fmaxf(m, __shfl_xor(m, 32));
    float sum = 0.f;
    #pragma unroll
    for (int mj = 0; mj < 4; ++mj) {
      float p0 = __expf(acc[mj][ni][0] - m);
      float p1 = __expf(acc[mj][ni][1] - m);
      float p2 = __expf(acc[mj][ni][2] - m);
      float p3 = __expf(acc[mj][ni][3] - m);
      sum += (p0 + p1) + (p2 + p3);
      u32 w0 = (u32)f2bf(p0) | ((u32)f2bf(p1) << 16);
      u32 w1 = (u32)f2bf(p2) | ((u32)f2bf(p3) << 16);
      int di = psb + ((i * 64 + mj * 16 + g * 4) ^ ((i & 7) << 3));
      *(u32*)&SH[di] = w0;
      *(u32*)&SH[di + 2] = w1;
    }
    sum += __shfl_xor(sum, 16);
    sum += __shfl_xor(sum, 32);
    sums[ni] = sum;
  }

  f32x4 accO[2][4] = {};
  #pragma unroll
  for (int ks = 0; ks < 2; ++ks) {
    bf16x8 av[2], bp[4];
    #pragma unroll
    for (int md = 0; md < 2; ++md)
      av[md] = *(const bf16x8*)&VT[(h * 32 + md * 16 + l15) * 72 + ks * 32 + g * 8];
    #pragma unroll
    for (int ni = 0; ni < 4; ++ni) {
      int i = ni * 16 + l15;
      bp[ni] = *(const bf16x8*)&SH[psb + ((i * 64 + ks * 32 + g * 8) ^ ((i & 7) << 3))];
    }
    #pragma unroll
    for (int md = 0; md < 2; ++md)
      #pragma unroll
      for (int ni = 0; ni < 4; ++ni)
        accO[md][ni] = __builtin_amdgcn_mfma_f32_16x16x32_bf16(av[md], bp[ni], accO[md][ni], 0, 0, 0);
  }

  #pragma unroll
  for (int md = 0; md < 2; ++md)
    #pragma unroll
    for (int ni = 0; ni < 4; ++ni) {
      float inv = 1.f / sums[ni];
      int i = ni * 16 + l15;
      #pragma unroll
      for (int r = 0; r < 4; r += 2) {
        int d = md * 16 + g * 4 + r;
        u32 wv = (u32)f2bf(accO[md][ni][r] * inv) |
                 ((u32)f2bf(accO[md][ni][r + 1] * inv) << 16);
        *(u32*)&SH[psb + i * 40 + d] = wv;
      }
    }
  for (int c = lane; c < 196; c += 64) {
    int i = c >> 2, off = (c & 3) * 8;
    uint4 v = *(const uint4*)&SH[psb + i * 40 + off];
    int yi = i / 7, xi = i - yi * 7;
    size_t t = wbase + yi * 56 + xi;
    *(uint4*)&aout[t * 192 + h * 32 + off] = v;
  }
}

// -------------------- host launch --------------------
extern "C" void kernel_launch(void* const* d_in, const int* in_sizes, int n_in,
                              void* d_out, int out_size, void* d_ws, size_t ws_size,
                              hipStream_t stream) {
  const float* x      = (const float*)d_in[0];
  const float* n1g    = (const float*)d_in[1];
  const float* n1b    = (const float*)d_in[2];
  const float* qkv_w  = (const float*)d_in[3];
  const float* qkv_b  = (const float*)d_in[4];
  const float* rpe    = (const float*)d_in[5];
  const float* proj_w = (const float*)d_in[6];
  const float* proj_b = (const float*)d_in[7];
  const float* n2g    = (const float*)d_in[8];
  const float* n2b    = (const float*)d_in[9];
  const float* fc1_w  = (const float*)d_in[10];
  const float* fc1_b  = (const float*)d_in[11];
  const float* fc2_w  = (const float*)d_in[12];
  const float* fc2_b  = (const float*)d_in[13];
  float* out = (float*)d_out;
  char* ws = (char*)d_ws;

  u16* qkvT  = (u16*)(ws + 0);          //  640x192 bf16
  u16* projT = (u16*)(ws + 245760);     //  256x192
  u16* fc1T  = (u16*)(ws + 344064);     //  768x192
  u16* fc2T  = (u16*)(ws + 638976);     //  192x768
  u16* ln1   = (u16*)(ws + 1048576);    //  TOKx192 bf16; reused as attn_out
  u16* qkvB  = (u16*)(ws + 39583744);   //  TOKx576 bf16; reused as h2
  u16* projO = (u16*)(ws + 155189248);  //  TOKx192 bf16
  u16* attnO = ln1;
  u16* h2    = qkvB;
  if (ws_size < 193724416u) return;

  transpose_pad<<<(640*192+255)/256, 256, 0, stream>>>(qkv_w,  qkvT, 576, 640, 192);
  transpose_pad<<<(256*192+255)/256, 256, 0, stream>>>(proj_w, projT, 192, 256, 192);
  transpose_pad<<<(768*192+255)/256, 256, 0, stream>>>(fc1_w,  fc1T, 768, 768, 192);
  transpose_pad<<<(192*768+255)/256, 256, 0, stream>>>(fc2_w,  fc2T, 192, 192, 768);

  ln_kernel<0><<<TOK/4, 256, 0, stream>>>(x, nullptr, n1g, n1b, ln1);

  gemm_kernel<MQKV><<<dim3(TOK/128, 5), 256, 0, stream>>>(
      ln1, qkvT, 192, 192, 576, 576, qkv_b, qkvB);

  attn_kernel<<<2048, 384, 0, stream>>>(qkvB, rpe, attnO);

  gemm_kernel<MPROJ><<<dim3(TOK/128, 2), 256, 0, stream>>>(
      attnO, projT, 192, 192, 192, 192, proj_b, projO);

  ln_kernel<1><<<TOK/4, 256, 0, stream>>>(x, projO, n2g, n2b, h2);

  mlp_kernel<<<TOK/128, 256, 0, stream>>>(
      h2, x, projO, fc1T, fc2T, fc1_b, fc2_b, out);
}

// Round 4
// 452.185 us; speedup vs baseline: 2.0174x; 2.0174x over previous
//
#include <hip/hip_runtime.h>
#include <cstdint>

using u16 = unsigned short;
using u32 = unsigned int;

typedef __bf16 bf16x8 __attribute__((ext_vector_type(8)));
typedef float f32x4 __attribute__((ext_vector_type(4)));

constexpr int TOK = 100352;                 // B * H * W
constexpr float SCALE_Q = 0.17677669529663687f;   // 1/sqrt(32)

__device__ __forceinline__ float bf2f(u16 u) {
  union { u32 i; float f; } z; z.i = ((u32)u) << 16; return z.f;
}
__device__ __forceinline__ u16 f2bf(float f) {
  union { float f; u32 i; } z; z.f = f;
  u32 r = z.i + 0x7FFFu + ((z.i >> 16) & 1u);
  return (u16)(r >> 16);
}

__device__ __forceinline__ void gload_lds16(const void* g, void* l) {
  __builtin_amdgcn_global_load_lds((const __attribute__((address_space(1))) void*)g,
                                   (__attribute__((address_space(3))) void*)l, 16, 0, 0);
}

// -------------------- weight transpose + zero-pad to Npad rows --------------------
__global__ void transpose_pad(const float* __restrict__ src, u16* __restrict__ dst,
                              int N, int Npad, int K) {
  int id = blockIdx.x * 256 + threadIdx.x;
  if (id >= Npad * K) return;
  int n = id / K, k = id - n * K;
  float v = (n < N) ? src[(size_t)k * N + n] : 0.f;
  dst[id] = f2bf(v);
}

// -------------------- layernorm (one wave per 192-wide row) --------------------
template<int MODE>  // 0: ln(x) ; 1: ln(x + proj_bf16)
__global__ __launch_bounds__(256) void ln_kernel(const float* __restrict__ x,
                                                 const u16* __restrict__ proj,
                                                 const float* __restrict__ g,
                                                 const float* __restrict__ b,
                                                 u16* __restrict__ out) {
  int row  = blockIdx.x * 4 + (threadIdx.x >> 6);
  int lane = threadIdx.x & 63;
  const float* xr = x + (size_t)row * 192;
  float v[3];
  #pragma unroll
  for (int t = 0; t < 3; ++t) {
    int c = lane + 64 * t;
    v[t] = xr[c];
    if (MODE == 1) v[t] += bf2f(proj[(size_t)row * 192 + c]);
  }
  float s = v[0] + v[1] + v[2];
  #pragma unroll
  for (int o = 32; o; o >>= 1) s += __shfl_xor(s, o);
  float mu = s * (1.f / 192.f);
  float q = 0.f;
  #pragma unroll
  for (int t = 0; t < 3; ++t) { float d = v[t] - mu; q += d * d; }
  #pragma unroll
  for (int o = 32; o; o >>= 1) q += __shfl_xor(q, o);
  float rs = rsqrtf(q * (1.f / 192.f) + 1e-5f);
  #pragma unroll
  for (int t = 0; t < 3; ++t) {
    int c = lane + 64 * t;
    out[(size_t)row * 192 + c] = f2bf((v[t] - mu) * rs * g[c] + b[c]);
  }
}

// -------------------- MFMA GEMM: C[M x N] = A[M x K] @ BT[N x K]^T + epilogue ----
enum { MQKV = 0, MPROJ = 1 };

template<int MODE>
__global__ __launch_bounds__(256) void gemm_kernel(
    const u16* __restrict__ A, const u16* __restrict__ BT,
    int K, int ldbt, int N, int ldc,
    const float* __restrict__ bias,
    u16* __restrict__ outb)
{
  __shared__ __align__(16) u16 As[128 * 32];
  __shared__ __align__(16) u16 Bs[128 * 32];
  int tid = threadIdx.x;
  int tileM = blockIdx.x * 128, tileN = blockIdx.y * 128;
  int lane = tid & 63, wave = tid >> 6;
  int wm = wave >> 1, wn = wave & 1;
  f32x4 acc[4][4] = {};

  int r0 = tid >> 2, kc = (tid & 3) * 8;
  const u16* Arow0 = A  + (size_t)(tileM + r0)      * K    + kc;
  const u16* Arow1 = A  + (size_t)(tileM + r0 + 64) * K    + kc;
  const u16* Brow0 = BT + (size_t)(tileN + r0)      * ldbt + kc;
  const u16* Brow1 = BT + (size_t)(tileN + r0 + 64) * ldbt + kc;
  u16* AsW0 = As + wave * 512;
  u16* AsW1 = As + 2048 + wave * 512;
  u16* BsW0 = Bs + wave * 512;
  u16* BsW1 = Bs + 2048 + wave * 512;

  for (int k0 = 0; k0 < K; k0 += 32) {
    __syncthreads();
    gload_lds16(Arow0 + k0, AsW0);
    gload_lds16(Arow1 + k0, AsW1);
    gload_lds16(Brow0 + k0, BsW0);
    gload_lds16(Brow1 + k0, BsW1);
    __syncthreads();
    bf16x8 af[4], bfr[4];
    #pragma unroll
    for (int mi = 0; mi < 4; ++mi)
      af[mi] = *(const bf16x8*)&As[(wm * 64 + mi * 16 + (lane & 15)) * 32 + (lane >> 4) * 8];
    #pragma unroll
    for (int ni = 0; ni < 4; ++ni)
      bfr[ni] = *(const bf16x8*)&Bs[(wn * 64 + ni * 16 + (lane & 15)) * 32 + (lane >> 4) * 8];
    #pragma unroll
    for (int mi = 0; mi < 4; ++mi)
      #pragma unroll
      for (int ni = 0; ni < 4; ++ni)
        acc[mi][ni] = __builtin_amdgcn_mfma_f32_16x16x32_bf16(af[mi], bfr[ni], acc[mi][ni], 0, 0, 0);
  }

  int rbase = tileM + wm * 64 + ((lane >> 4) << 2);
  int cbase = tileN + wn * 64 + (lane & 15);
  #pragma unroll
  for (int ni = 0; ni < 4; ++ni) {
    int col = cbase + ni * 16;
    if (col >= N) continue;
    float bv = bias[col];
    #pragma unroll
    for (int mi = 0; mi < 4; ++mi) {
      #pragma unroll
      for (int i = 0; i < 4; ++i) {
        int row = rbase + mi * 16 + i;
        float v = acc[mi][ni][i] + bv;
        if (MODE == MQKV && col < 192) v *= SCALE_Q;
        outb[(size_t)row * ldc + col] = f2bf(v);
      }
    }
  }
}

// -------------------- fused MLP v2: out = x + proj + fc2(gelu(fc1(h2))) -------
// 1568 blocks x 256 threads (4 waves). 64 rows/block, wave owns 16 rows.
// X lives in REGISTERS (6 frags/wave). 24 chunks of 32 gelu-cols; W1/W2 chunk
// staged to padded LDS (29.1 KB total -> multi-block/CU occupancy).
constexpr int WS1 = 194;   // W1 row stride (97 dw % 32 == 1, conflict-free)
constexpr int WS2 = 34;    // W2 row stride (17 dw)
constexpr int GS  = 34;    // G row stride

__global__ __launch_bounds__(256, 4) void mlp_kernel(
    const u16* __restrict__ h2, const float* __restrict__ x,
    const u16* __restrict__ projO,
    const u16* __restrict__ fc1T,   // [768][192] bf16
    const u16* __restrict__ fc2T,   // [192][768] bf16
    const float* __restrict__ fc1b, const float* __restrict__ fc2b,
    float* __restrict__ out)
{
  __shared__ __align__(16) u16 W1[32 * WS1];        // 12416 B
  __shared__ __align__(16) u16 W2[192 * WS2];       // 13056 B
  __shared__ __align__(16) u16 G[4 * 16 * GS];      //  4352 B

  int tid = threadIdx.x, lane = tid & 63, wave = tid >> 6;
  int g = lane >> 4, l15 = lane & 15;
  size_t row0 = (size_t)blockIdx.x * 64;
  size_t myrow = row0 + wave * 16 + l15;

  // X fragments in registers: 16 rows/wave x 192 k
  bf16x8 xf[6];
  #pragma unroll
  for (int ks = 0; ks < 6; ++ks)
    xf[ks] = *(const bf16x8*)&h2[myrow * 192 + ks * 32 + g * 8];

  f32x4 accO[12] = {};
  u16* Gw = G + wave * (16 * GS);

  for (int ch = 0; ch < 24; ++ch) {
    __syncthreads();   // prior chunk's W reads done
    // stage W1 chunk [32 gc][192 k]: 768 16B slots
    {
      int c = tid;                                   // 256 threads, 3 slots each
      #pragma unroll
      for (int it = 0; it < 3; ++it, c += 256) {
        int r = c / 24, kc = c - r * 24;
        *(uint4*)&W1[r * WS1 + kc * 8] =
            *(const uint4*)&fc1T[((size_t)(ch * 32 + r)) * 192 + kc * 8];
      }
    }
    // stage W2 chunk [192 oc][32 k]: 768 16B slots
    {
      int c = tid;
      #pragma unroll
      for (int it = 0; it < 3; ++it, c += 256) {
        int r = c >> 2, kc = c & 3;
        *(uint4*)&W2[r * WS2 + kc * 8] =
            *(const uint4*)&fc2T[(size_t)r * 768 + ch * 32 + kc * 8];
      }
    }
    __syncthreads();

    // ---- fc1: S[16 r][32 gc] = X @ W1c^T ----
    f32x4 acc1[2] = {};
    #pragma unroll
    for (int ks = 0; ks < 6; ++ks) {
      bf16x8 wf0 = *(const bf16x8*)&W1[(l15)      * WS1 + ks * 32 + g * 8];
      bf16x8 wf1 = *(const bf16x8*)&W1[(16 + l15) * WS1 + ks * 32 + g * 8];
      acc1[0] = __builtin_amdgcn_mfma_f32_16x16x32_bf16(xf[ks], wf0, acc1[0], 0, 0, 0);
      acc1[1] = __builtin_amdgcn_mfma_f32_16x16x32_bf16(xf[ks], wf1, acc1[1], 0, 0, 0);
    }

    // ---- gelu + write wave-private G[16 r][32 gc] ----
    #pragma unroll
    for (int ni = 0; ni < 2; ++ni) {
      float bv = fc1b[ch * 32 + ni * 16 + l15];
      #pragma unroll
      for (int r = 0; r < 4; ++r) {
        float v = acc1[ni][r] + bv;
        v = 0.5f * v * (1.f + erff(v * 0.70710678118f));
        Gw[(g * 4 + r) * GS + ni * 16 + l15] = f2bf(v);
      }
    }
    asm volatile("s_waitcnt lgkmcnt(0)" ::: "memory");
    __builtin_amdgcn_sched_barrier(0);

    // ---- fc2 accumulate: out[16 r][192 oc] += G @ W2c^T ----
    bf16x8 gf = *(const bf16x8*)&Gw[l15 * GS + g * 8];
    #pragma unroll
    for (int ni = 0; ni < 12; ++ni) {
      bf16x8 wf = *(const bf16x8*)&W2[(ni * 16 + l15) * WS2 + g * 8];
      accO[ni] = __builtin_amdgcn_mfma_f32_16x16x32_bf16(gf, wf, accO[ni], 0, 0, 0);
    }
  }

  // ---- epilogue: out = accO + fc2_b + x + projO ----
  #pragma unroll
  for (int ni = 0; ni < 12; ++ni) {
    int oc = ni * 16 + l15;
    float bv = fc2b[oc];
    #pragma unroll
    for (int r = 0; r < 4; ++r) {
      size_t row = row0 + wave * 16 + g * 4 + r;
      size_t o = row * 192 + oc;
      out[o] = accO[ni][r] + bv + x[o] + bf2f(projO[o]);
    }
  }
}

// -------------------- MFMA windowed attention --------------------
__global__ __launch_bounds__(384, 3) void attn_kernel(const u16* __restrict__ qkv,
                                                      const float* __restrict__ rpe,
                                                      u16* __restrict__ aout) {
  __shared__ __align__(16) u16 SH[64 * 384];
  __shared__ __align__(16) u16 VT[192 * 72];
  __shared__ float RPE[1014];

  int tid = threadIdx.x;
  int win = blockIdx.x;
  int b = win >> 6, rem = win & 63, wh = rem >> 3, ww = rem & 7;
  const size_t wbase = (size_t)b * 3136 + (size_t)(wh * 7) * 56 + ww * 7;

  for (int c = tid; c < 2352; c += 384) {
    int tkn = c / 48, off = (c - tkn * 48) * 8;
    int yi = tkn / 7, xi = tkn - yi * 7;
    size_t t = wbase + yi * 56 + xi;
    uint4 v = *(const uint4*)&qkv[t * 576 + off];
    *(uint4*)&SH[(tkn * 384 + off) ^ ((tkn & 7) << 3)] = v;
  }
  for (int c = tid; c < 1176; c += 384) {
    int tkn = c / 24, d0 = (c - tkn * 24) * 8;
    int yi = tkn / 7, xi = tkn - yi * 7;
    size_t t = wbase + yi * 56 + xi;
    uint4 v = *(const uint4*)&qkv[t * 576 + 384 + d0];
    const u16* e = (const u16*)&v;
    #pragma unroll
    for (int u = 0; u < 8; ++u) VT[(d0 + u) * 72 + tkn] = e[u];
  }
  for (int c = tid; c < 2880; c += 384) {
    int d = c / 15, n = 49 + (c - d * 15);
    VT[d * 72 + n] = 0;
  }
  for (int c = tid; c < 1014; c += 384) RPE[c] = rpe[c];
  __syncthreads();

  int wave = tid >> 6, lane = tid & 63;
  int g = lane >> 4, l15 = lane & 15;
  int h = wave;

  bf16x8 afk[4], bfq[4];
  #pragma unroll
  for (int f = 0; f < 4; ++f) {
    int row = f * 16 + l15;
    int sw = (row & 7) << 3;
    afk[f] = *(const bf16x8*)&SH[(row * 384 + 192 + h * 32 + g * 8) ^ sw];
    bfq[f] = *(const bf16x8*)&SH[(row * 384 +       h * 32 + g * 8) ^ sw];
  }
  f32x4 acc[4][4] = {};
  #pragma unroll
  for (int mj = 0; mj < 4; ++mj)
    #pragma unroll
    for (int ni = 0; ni < 4; ++ni)
      acc[mj][ni] = __builtin_amdgcn_mfma_f32_16x16x32_bf16(afk[mj], bfq[ni], acc[mj][ni], 0, 0, 0);
  __syncthreads();

  const int psb = wave * 4096;
  float sums[4];
  #pragma unroll
  for (int ni = 0; ni < 4; ++ni) {
    int i = ni * 16 + l15;
    int yi = i / 7, xi = i - yi * 7;
    #pragma unroll
    for (int mj = 0; mj < 4; ++mj)
      #pragma unroll
      for (int r = 0; r < 4; ++r) {
        int j = mj * 16 + g * 4 + r;
        int yj = j / 7, xj = j - yj * 7;
        int idx = (yi - yj + 6) * 13 + (xi - xj + 6);
        idx = max(0, min(idx, 168));
        float s = acc[mj][ni][r] + RPE[idx * 6 + h];
        acc[mj][ni][r] = (j < 49) ? s : -1e30f;
      }
    float m = -1e30f;
    #pragma unroll
    for (int mj = 0; mj < 4; ++mj) {
      f32x4 a = acc[mj][ni];
      m = fmaxf(m, fmaxf(fmaxf(a[0], a[1]), fmaxf(a[2], a[3])));
    }
    m = fmaxf(m, __shfl_xor(m, 16));
    m = fmaxf(m, __shfl_xor(m, 32));
    float sum = 0.f;
    #pragma unroll
    for (int mj = 0; mj < 4; ++mj) {
      float p0 = __expf(acc[mj][ni][0] - m);
      float p1 = __expf(acc[mj][ni][1] - m);
      float p2 = __expf(acc[mj][ni][2] - m);
      float p3 = __expf(acc[mj][ni][3] - m);
      sum += (p0 + p1) + (p2 + p3);
      u32 w0 = (u32)f2bf(p0) | ((u32)f2bf(p1) << 16);
      u32 w1 = (u32)f2bf(p2) | ((u32)f2bf(p3) << 16);
      int di = psb + ((i * 64 + mj * 16 + g * 4) ^ ((i & 7) << 3));
      *(u32*)&SH[di] = w0;
      *(u32*)&SH[di + 2] = w1;
    }
    sum += __shfl_xor(sum, 16);
    sum += __shfl_xor(sum, 32);
    sums[ni] = sum;
  }

  f32x4 accO[2][4] = {};
  #pragma unroll
  for (int ks = 0; ks < 2; ++ks) {
    bf16x8 av[2], bp[4];
    #pragma unroll
    for (int md = 0; md < 2; ++md)
      av[md] = *(const bf16x8*)&VT[(h * 32 + md * 16 + l15) * 72 + ks * 32 + g * 8];
    #pragma unroll
    for (int ni = 0; ni < 4; ++ni) {
      int i = ni * 16 + l15;
      bp[ni] = *(const bf16x8*)&SH[psb + ((i * 64 + ks * 32 + g * 8) ^ ((i & 7) << 3))];
    }
    #pragma unroll
    for (int md = 0; md < 2; ++md)
      #pragma unroll
      for (int ni = 0; ni < 4; ++ni)
        accO[md][ni] = __builtin_amdgcn_mfma_f32_16x16x32_bf16(av[md], bp[ni], accO[md][ni], 0, 0, 0);
  }

  #pragma unroll
  for (int md = 0; md < 2; ++md)
    #pragma unroll
    for (int ni = 0; ni < 4; ++ni) {
      float inv = 1.f / sums[ni];
      int i = ni * 16 + l15;
      #pragma unroll
      for (int r = 0; r < 4; r += 2) {
        int d = md * 16 + g * 4 + r;
        u32 wv = (u32)f2bf(accO[md][ni][r] * inv) |
                 ((u32)f2bf(accO[md][ni][r + 1] * inv) << 16);
        *(u32*)&SH[psb + i * 40 + d] = wv;
      }
    }
  for (int c = lane; c < 196; c += 64) {
    int i = c >> 2, off = (c & 3) * 8;
    uint4 v = *(const uint4*)&SH[psb + i * 40 + off];
    int yi = i / 7, xi = i - yi * 7;
    size_t t = wbase + yi * 56 + xi;
    *(uint4*)&aout[t * 192 + h * 32 + off] = v;
  }
}

// -------------------- host launch --------------------
extern "C" void kernel_launch(void* const* d_in, const int* in_sizes, int n_in,
                              void* d_out, int out_size, void* d_ws, size_t ws_size,
                              hipStream_t stream) {
  const float* x      = (const float*)d_in[0];
  const float* n1g    = (const float*)d_in[1];
  const float* n1b    = (const float*)d_in[2];
  const float* qkv_w  = (const float*)d_in[3];
  const float* qkv_b  = (const float*)d_in[4];
  const float* rpe    = (const float*)d_in[5];
  const float* proj_w = (const float*)d_in[6];
  const float* proj_b = (const float*)d_in[7];
  const float* n2g    = (const float*)d_in[8];
  const float* n2b    = (const float*)d_in[9];
  const float* fc1_w  = (const float*)d_in[10];
  const float* fc1_b  = (const float*)d_in[11];
  const float* fc2_w  = (const float*)d_in[12];
  const float* fc2_b  = (const float*)d_in[13];
  float* out = (float*)d_out;
  char* ws = (char*)d_ws;

  u16* qkvT  = (u16*)(ws + 0);          //  640x192 bf16
  u16* projT = (u16*)(ws + 245760);     //  256x192
  u16* fc1T  = (u16*)(ws + 344064);     //  768x192
  u16* fc2T  = (u16*)(ws + 638976);     //  192x768
  u16* ln1   = (u16*)(ws + 1048576);    //  TOKx192 bf16; reused as attn_out
  u16* qkvB  = (u16*)(ws + 39583744);   //  TOKx576 bf16; reused as h2
  u16* projO = (u16*)(ws + 155189248);  //  TOKx192 bf16
  u16* attnO = ln1;
  u16* h2    = qkvB;
  if (ws_size < 193724416u) return;

  transpose_pad<<<(640*192+255)/256, 256, 0, stream>>>(qkv_w,  qkvT, 576, 640, 192);
  transpose_pad<<<(256*192+255)/256, 256, 0, stream>>>(proj_w, projT, 192, 256, 192);
  transpose_pad<<<(768*192+255)/256, 256, 0, stream>>>(fc1_w,  fc1T, 768, 768, 192);
  transpose_pad<<<(192*768+255)/256, 256, 0, stream>>>(fc2_w,  fc2T, 192, 192, 768);

  ln_kernel<0><<<TOK/4, 256, 0, stream>>>(x, nullptr, n1g, n1b, ln1);

  gemm_kernel<MQKV><<<dim3(TOK/128, 5), 256, 0, stream>>>(
      ln1, qkvT, 192, 192, 576, 576, qkv_b, qkvB);

  attn_kernel<<<2048, 384, 0, stream>>>(qkvB, rpe, attnO);

  gemm_kernel<MPROJ><<<dim3(TOK/128, 2), 256, 0, stream>>>(
      attnO, projT, 192, 192, 192, 192, proj_b, projO);

  ln_kernel<1><<<TOK/4, 256, 0, stream>>>(x, projO, n2g, n2b, h2);

  mlp_kernel<<<TOK/64, 256, 0, stream>>>(
      h2, x, projO, fc1T, fc2T, fc1_b, fc2_b, out);
}